// Round 16
// baseline (3353.892 us; speedup 1.0000x reference)
//
#include <hip/hip_runtime.h>

// HSMM forward log-likelihood, B=32, T=8192, K=128, Dmax=128.
// One block per sequence (32 blocks, 512 threads = 8 waves, 2/SIMD).
// R17 = R15 (verified, 3312us, absmax 0.0) + ONE change:
//   HALF-LOAD s-exchange: lanes l and l^8 (same chunk cc, same DPP row)
//   each read HALF the chunk (2 ds_read_b128 instead of 4) and exchange
//   halves via v_mov_dpp row_ror:8 (0x128). A-const order permuted per
//   lane so vp-slot -> source mapping is exact. Cuts the post-barrier
//   LDS burst from ~32 b128/CU-step to ~16 (the current binding term).
// Everything else R15-verbatim: slow gauge (K = M^(-1/16), 1 LDS scalar
// per 16 steps), adjacent pairing, R10 ordering, DPP reduces, ring/ee.

typedef float f32x2 __attribute__((ext_vector_type(2)));

#define T_LEN 8192
#define KST   128
#define NTHR  512
#define SROW  160   // shat buffer: 8 groups x (16 data + 4 pad) floats

__device__ __forceinline__ void barrier_nodrain() {
  asm volatile("s_waitcnt lgkmcnt(0)\n\ts_barrier" ::: "memory");
}

template <int CTRL>
__device__ __forceinline__ float dpp_mov(float x) {
  int y = __builtin_amdgcn_update_dpp(0, __builtin_bit_cast(int, x),
                                      CTRL, 0xF, 0xF, true);
  return __builtin_bit_cast(float, y);
}
template <int CTRL>
__device__ __forceinline__ f32x2 dpp_addv(f32x2 x) {
  f32x2 y;
  y.x = dpp_mov<CTRL>(x.x);
  y.y = dpp_mov<CTRL>(x.y);
  return x + y;
}
// xor-8 within a 16-lane row (row_ror:8 = 0x128): fetch partner half
__device__ __forceinline__ f32x2 dpp_swap8(f32x2 x) {
  f32x2 y;
  y.x = dpp_mov<0x128>(x.x);
  y.y = dpp_mov<0x128>(x.y);
  return y;
}

__device__ __forceinline__ void pk_fma(f32x2& d, f32x2 a, f32x2 b) {
  asm("v_pk_fma_f32 %0, %1, %2, %0" : "+v"(d) : "v"(a), "v"(b));
}
// acc.lo += a.lo * b.lo; acc.hi += a.hi * b.lo   (broadcast b.lo)
__device__ __forceinline__ void pk_fma_blo(f32x2& d, f32x2 a, f32x2 b) {
  asm("v_pk_fma_f32 %0, %1, %2, %0 op_sel:[0,0,0] op_sel_hi:[1,0,1]"
      : "+v"(d) : "v"(a), "v"(b));
}
// acc.lo += a.lo * b.hi; acc.hi += a.hi * b.hi   (broadcast b.hi)
__device__ __forceinline__ void pk_fma_bhi(f32x2& d, f32x2 a, f32x2 b) {
  asm("v_pk_fma_f32 %0, %1, %2, %0 op_sel:[0,1,0] op_sel_hi:[1,1,1]"
      : "+v"(d) : "v"(a), "v"(b));
}
__device__ __forceinline__ f32x2 pk_mul(f32x2 a, f32x2 b) {
  f32x2 d;
  asm("v_pk_mul_f32 %0, %1, %2" : "=v"(d) : "v"(a), "v"(b));
  return d;
}

template <int U>
__device__ __forceinline__ void step_body(
    int t0, int cc, int w, int L, int sel, int c2, int cc16, int hb,
    const float* __restrict__ pB,
    f32x2 (&qq)[16], const f32x2 (&Apl)[8], const f32x2 (&Aph)[8],
    f32x2 (&ee)[16], f32x2 (&lbp)[16],
    int& off,
    f32x2& psi, f32x2& invpsi, f32x2& exq, f32x2& Kv,
    float& Ctot, f32x2& skeep,
    f32x2 expD0p, f32x2 pexpp, int swaddr,
    float* s_flat, float* m_sc, const float* ep_flat)
{
  const int t = t0 + U;
  const f32x2 expB = exq;   // exp(logB[t, pair]), computed last step

  // ---- issue memory early (R10 ordering) ----
  int tn = t + 16; tn = (tn < T_LEN) ? tn : (T_LEN - 1);
  lbp[U] = *reinterpret_cast<const f32x2*>(pB + (size_t)tn * KST);

  // slow gauge: once per block, read proxy max, set K and Ctot
  if (U == 0) {
    float M = m_sc[0];
    M = fminf(fmaxf(M, 1e-30f), 1e30f);   // exact free gauge; NaN firewall
    float l2 = __log2f(M);
    Ctot += l2 * 0.69314718056f;
    float K = __builtin_amdgcn_exp2f(l2 * -0.0625f);   // M^(-1/16)
    Kv = f32x2{K, K};
  }

  // shat(t-1): HALF the chunk (2 b128); partner half arrives via DPP
  const float* sp = s_flat + (U & 1) * SROW + 20 * cc + 8 * hb;
  const float4 a0 = *(const float4*)(sp + 0);
  const float4 a1 = *(const float4*)(sp + 4);

  // ee rotation read for t+1 (byte-offset walk; skew changes at U==15)
  if (U == 15) {
    int rn = (t0 + 16 - cc16) & 127;
    int cl = (c2 + 4 * ((rn >> 4) & 7)) & 127;
    off = rn * 512 + cl * 4;
  } else {
    off = (off + 512) & 0xFFFF;
  }
  const f32x2 ne =
      *reinterpret_cast<const f32x2*>(reinterpret_cast<const char*>(ep_flat) + off);

  // ---- duration dot: 16 pk over state-paired ring (2 chains) ----
  f32x2 da = pk_mul(qq[0], ee[(0 - U) & 15]);
  f32x2 db = pk_mul(qq[1], ee[(1 - U) & 15]);
#pragma unroll
  for (int k = 2; k < 16; k += 2) {
    pk_fma(da, qq[k],     ee[(k - U) & 15]);
    pk_fma(db, qq[k + 1], ee[(k + 1 - U) & 15]);
  }
  f32x2 dp = da + db;

  // ---- gauge update: one pk_mul by the in-register block constant ----
  psi = pk_mul(psi, pk_mul(expB, Kv));

  // ---- source pairs: own half direct, partner half via row_ror:8 ----
  const f32x2 p0 = {a0.x, a0.y}, p1 = {a0.z, a0.w};
  const f32x2 p2 = {a1.x, a1.y}, p3 = {a1.z, a1.w};
  const f32x2 p4 = dpp_swap8(p0), p5 = dpp_swap8(p1);
  const f32x2 p6 = dpp_swap8(p2), p7 = dpp_swap8(p3);

  // ---- matvec: 16 pk, dests (2m,2m+1) in pk lanes, src-broadcast ----
  // A-consts were permuted at init to match [own(4), swapped(4)] order.
  f32x2 ma = {0.0f, 0.0f}, mb = {0.0f, 0.0f};
  pk_fma_blo(ma, Apl[0], p0); pk_fma_bhi(mb, Aph[0], p0);
  pk_fma_blo(ma, Apl[1], p1); pk_fma_bhi(mb, Aph[1], p1);
  pk_fma_blo(ma, Apl[2], p2); pk_fma_bhi(mb, Aph[2], p2);
  pk_fma_blo(ma, Apl[3], p3); pk_fma_bhi(mb, Aph[3], p3);
  pk_fma_blo(ma, Apl[4], p4); pk_fma_bhi(mb, Aph[4], p4);
  pk_fma_blo(ma, Apl[5], p5); pk_fma_bhi(mb, Aph[5], p5);
  pk_fma_blo(ma, Apl[6], p6); pk_fma_bhi(mb, Aph[6], p6);
  pk_fma_blo(ma, Apl[7], p7); pk_fma_bhi(mb, Aph[7], p7);
  f32x2 mp = ma + mb;

  // ---- reduce over 8 chunk lanes (bits 0..2): xor1, xor2, mirror-8 ----
  dp = dpp_addv<0xB1>(dp); dp = dpp_addv<0x4E>(dp); dp = dpp_addv<0x141>(dp);
  mp = dpp_addv<0xB1>(mp); mp = dpp_addv<0x4E>(mp); mp = dpp_addv<0x141>(mp);

  // ---- insert pair + shat pair (group-uniform) ----
  f32x2 Qins = pk_mul(mp, invpsi);
  if (U == 0) { if (t0 == 0) Qins = pexpp; }
  f32x2 sacc = dp;
  pk_fma(sacc, Qins, expD0p);
  const f32x2 s = pk_mul(sacc, psi);

  // publish shat pair early: one b64 per group
  if (cc == 0)
    *reinterpret_cast<f32x2*>(s_flat + ((U + 1) & 1) * SROW + swaddr) = s;

  // proxy max: ONCE per block (U==15), wave 0, R10-verified chain
  if (U == 15 && w == 0) {
    float sm = fmaxf(s.x, s.y);
    sm = fmaxf(sm, dpp_mov<0x140>(sm));   // row_mirror
    sm = fmaxf(sm, dpp_mov<0x142>(sm));   // row_bcast15
    sm = fmaxf(sm, dpp_mov<0x143>(sm));   // row_bcast31 -> lane 63
    if (L == 63) m_sc[0] = sm;
  }

  // ---- thread-local tail ----
  // exp for NEXT step (loaded 15 steps ago -> arrived)
  exq.x = __expf(lbp[(U + 1) & 15].x);
  exq.y = __expf(lbp[(U + 1) & 15].y);

  // ring insert: slot p = t&127 -> chunk sel = (t>>4)&7, reg U
  if (sel == cc) qq[U] = Qins;

  // commit ee rotation (old slot fully consumed by the dot above)
  ee[(15 - U) & 15] = ne;

  // fold gauge into ring every 16 steps
  if (U == 15) {
#pragma unroll
    for (int k = 0; k < 16; ++k) qq[k] = pk_mul(qq[k], psi);
    psi = f32x2{1.0f, 1.0f};
  }
  invpsi.x = __builtin_amdgcn_rcpf(psi.x);
  invpsi.y = __builtin_amdgcn_rcpf(psi.y);

  skeep = s;
  barrier_nodrain();
}

__global__ __launch_bounds__(NTHR, 1) void hsmm_fwd_kernel(
    const float* __restrict__ logB_all,
    const float* __restrict__ logpi,
    const float* __restrict__ logA,
    const float* __restrict__ logD,
    float* __restrict__ out)
{
  const int tid = threadIdx.x;
  const int L   = tid & 63;
  const int w   = tid >> 6;
  const int cc  = L & 7;            // source chunk (8 lanes per group)
  const int g   = L >> 3;           // dest group 0..7
  const int hb  = g & 1;            // half-select for the split s-read
  const int m   = 8 * w + g;        // pair index: states (2m, 2m+1)
  const int j0  = 2 * m;
  const int b   = blockIdx.x;
  const float* __restrict__ pB = logB_all + (size_t)b * T_LEN * KST + j0;

  // epair[d][col(m,d) + {0,1}] = (expD[2m][d], expD[2m+1][d]);
  // col(m,d) = (2m + 4*((d>>4)&7)) & 127. Row 0 zeroed (stale-slot kill).
  __shared__ __align__(16) float epair[128 * 128];
  __shared__ __align__(16) float s_lds[2 * SROW];  // pair-interleaved shat
  __shared__ float m_sc[1];                        // block proxy max
  __shared__ float fin[8];

  // ---- init ----
  for (int idx = tid; idx < 128 * 128; idx += NTHR) {
    int d = idx >> 7, r = idx & 127;
    int mm = r >> 1, hbb = r & 1;
    int col = ((2 * mm + 4 * ((d >> 4) & 7)) & 127) + hbb;
    epair[(d << 7) + col] = (d == 0) ? 0.0f : __expf(logD[(2 * mm + hbb) * 128 + d]);
  }
  if (tid < 2 * SROW) s_lds[tid] = 0.0f;
  if (tid == 0) m_sc[0] = 1.0f;

  // matvec constants, permuted to the lane's vp order:
  //   slot r<4: source-pair kk = 4*hb + r (own half)
  //   slot r>=4: kk = 4*(1-hb) + (r-4)   (partner half via DPP)
  f32x2 Apl[8], Aph[8];
#pragma unroll
  for (int r = 0; r < 8; ++r) {
    int kk = (r < 4) ? (4 * hb + r) : (4 * (1 - hb) + (r - 4));
    int se = 16 * cc + 2 * kk;
    Apl[r].x = __expf(logA[se * KST + j0]);
    Apl[r].y = __expf(logA[se * KST + j0 + 1]);
    Aph[r].x = __expf(logA[(se + 1) * KST + j0]);
    Aph[r].y = __expf(logA[(se + 1) * KST + j0 + 1]);
  }
  const f32x2 expD0p = {__expf(logD[j0 * 128]), __expf(logD[(j0 + 1) * 128])};
  const f32x2 pexpp  = {__expf(logpi[j0]), __expf(logpi[j0 + 1])};
  const int   swaddr = 20 * w + 2 * g;   // pair m at 20*(m>>3) + 2*(m&7)
  const int   c2     = 2 * m;            // epair column base
  const int   cc16   = 16 * cc;

  f32x2 qq[16];
#pragma unroll
  for (int k = 0; k < 16; ++k) qq[k] = f32x2{0.0f, 0.0f};

  __syncthreads();  // table + buffers ready

  // ee init for t=0: ee[k] = epair row (-(16cc+k))&127, col base c2
  f32x2 ee[16];
#pragma unroll
  for (int k = 0; k < 16; ++k) {
    int rA = (-(cc16 + k)) & 127;
    int cl = (c2 + 4 * ((rA >> 4) & 7)) & 127;
    ee[k] = *reinterpret_cast<const f32x2*>(&epair[(rA << 7) + cl]);
  }

  // rotation byte offset, pre-decremented (body adds 512 -> row t+1-16cc)
  int off;
  {
    int r0 = (-cc16) & 127;
    int cl = (c2 + 4 * ((r0 >> 4) & 7)) & 127;
    off = r0 * 512 + cl * 4;
  }

  // logB pair prefetch ring (16 ahead)
  f32x2 lbp[16];
#pragma unroll
  for (int u = 0; u < 16; ++u)
    lbp[u] = *reinterpret_cast<const f32x2*>(pB + (size_t)u * KST);

  f32x2 psi = {1.0f, 1.0f}, invpsi = {1.0f, 1.0f};
  f32x2 Kv  = {1.0f, 1.0f};
  float Ctot = 0.0f;
  f32x2 skeep = {0.0f, 0.0f};
  f32x2 exq = {__expf(lbp[0].x), __expf(lbp[0].y)};

#pragma unroll 1
  for (int t0 = 0; t0 < T_LEN; t0 += 16) {
    const int sel = (t0 >> 4) & 7;   // ring chunk receiving this block
#define STEP(U) step_body<U>(t0, cc, w, L, sel, c2, cc16, hb, pB, qq, Apl,    \
                             Aph, ee, lbp, off, psi, invpsi, exq, Kv, Ctot,   \
                             skeep, expD0p, pexpp, swaddr, s_lds, m_sc, epair)
    STEP(0);  STEP(1);  STEP(2);  STEP(3);
    STEP(4);  STEP(5);  STEP(6);  STEP(7);
    STEP(8);  STEP(9);  STEP(10); STEP(11);
    STEP(12); STEP(13); STEP(14); STEP(15);
#undef STEP
  }

  // ---- final: out[b] = Ctot + log sum_j shat[j] (each pair once: cc==0) --
  float v = (cc == 0) ? (skeep.x + skeep.y) : 0.0f;
  v += __shfl_xor(v, 8);  v += __shfl_xor(v, 16); v += __shfl_xor(v, 32);
  if (L == 0) fin[w] = v;
  __syncthreads();
  if (tid == 0) {
    float tot = 0.0f;
#pragma unroll
    for (int i = 0; i < 8; ++i) tot += fin[i];
    out[b] = Ctot + __logf(tot);
  }
}

extern "C" void kernel_launch(void* const* d_in, const int* in_sizes, int n_in,
                              void* d_out, int out_size, void* d_ws, size_t ws_size,
                              hipStream_t stream) {
  const float* logB  = (const float*)d_in[0];
  const float* logpi = (const float*)d_in[1];
  const float* logA  = (const float*)d_in[2];
  const float* logD  = (const float*)d_in[3];
  float* out = (float*)d_out;
  const int B = out_size;  // 32
  hipLaunchKernelGGL(hsmm_fwd_kernel, dim3(B), dim3(NTHR), 0, stream,
                     logB, logpi, logA, logD, out);
}